// Round 6
// baseline (50.803 us; speedup 1.0000x reference)
//
#include <hip/hip_runtime.h>

#define NROIS 64
#define CCH   64
#define OUTD  128
#define NT    1024   // threads per block

typedef float f32x4 __attribute__((ext_vector_type(4)));

// One 2x align_corners=True bilinear upsample step inside LDS.
// src: N x N, dst: 2N x 2N. Matches reference lin1d(axis=H) then lin1d(axis=W).
template <int N>
__device__ __forceinline__ void up2x_lds(const float* __restrict__ src,
                                         float* __restrict__ dst, int tid) {
    constexpr int N2 = 2 * N;
    constexpr float ratio = (float)(N - 1) / (float)(N2 - 1);
    for (int idx = tid; idx < N2 * N2; idx += NT) {
        int i = idx / N2;
        int j = idx - i * N2;
        float si = (float)i * ratio;
        int i0 = (int)si;
        float ti = si - (float)i0;
        int i1 = min(i0 + 1, N - 1);
        float sj = (float)j * ratio;
        int j0 = (int)sj;
        float tj = sj - (float)j0;
        int j1 = min(j0 + 1, N - 1);
        float a00 = src[i0 * N + j0], a10 = src[i1 * N + j0];
        float a01 = src[i0 * N + j1], a11 = src[i1 * N + j1];
        float c0 = a00 + ti * (a10 - a00);
        float c1 = a01 + ti * (a11 - a01);
        dst[idx] = c0 + tj * (c1 - c0);
    }
}

__global__ __launch_bounds__(NT) void roi_level_kernel(
    const float* __restrict__ x0, const float* __restrict__ x1,
    const float* __restrict__ x2, const float* __restrict__ x3,
    const float* __restrict__ rois, float* __restrict__ out) {
    __shared__ float s16[16 * 16];
    __shared__ float s32[32 * 32];
    __shared__ float s64[64 * 64];

    const int c   = blockIdx.x;   // channel (fastest -> contiguous 64KB writes)
    const int r   = blockIdx.y;   // roi
    const int tid = threadIdx.x;

    // ---- per-ROI params (block-uniform) ----
    const float* R = rois + r * 5;
    const float px = R[1], py = R[2], w = R[3], h = R[4];
    const int   b  = (int)R[0];
    float s = sqrtf(w * h);
    float target = floorf(4.0f + log2f(s / 224.0f + 1e-6f));
    target = fminf(fmaxf(target, 2.0f), 5.0f);
    const int level = (int)target - 2;               // 0..3
    const float scale = 1.0f / (float)(4 << level);
    const int xl = ((int)(px * scale)) & ~1;
    const int yl = ((int)(py * scale)) & ~1;
    const float* feat = (level == 0) ? x0 : (level == 1) ? x1
                       : (level == 2) ? x2 : x3;
    const int H = 256 >> level;

    // ---- load 16x16 crop for this channel into LDS ----
    if (tid < 256) {
        int i = tid >> 4, j = tid & 15;
        s16[tid] = feat[(((size_t)b * CCH + c) * H + (size_t)(yl + i)) * H + (xl + j)];
    }
    __syncthreads();

    // ---- pre-upsample steps in LDS ----
    if (level >= 2) { up2x_lds<16>(s16, s32, tid); __syncthreads(); }
    if (level == 3) { up2x_lds<32>(s32, s64, tid); __syncthreads(); }

    // ---- final step fused with the padded 128x128 write ----
    f32x4* outp = (f32x4*)(out + ((size_t)(r * CCH + c) << 14));  // 128*128 plane

    if (level == 0) {
        for (int k = 0; k < 4; ++k) {
            int idx  = tid + k * NT;          // 0..4095 float4 slots
            int row  = idx >> 5;              // 32 float4 per row
            int col4 = idx & 31;
            f32x4 v = (f32x4)(0.f);
            if (row < 16 && col4 < 4) {
                const float* p = s16 + row * 16 + col4 * 4;
                v = (f32x4){p[0], p[1], p[2], p[3]};
            }
            outp[idx] = v;
        }
    } else {
        const float* src = (level == 1) ? s16 : (level == 2) ? s32 : s64;
        const int   n     = 8 << level;       // source grid dim
        const int   sz    = n * 2;            // nonzero extent (32/64/128)
        const float ratio = (float)(n - 1) / (float)(2 * n - 1);
        for (int k = 0; k < 4; ++k) {
            int idx  = tid + k * NT;
            int row  = idx >> 5;
            int jb   = (idx & 31) * 4;
            f32x4 v = (f32x4)(0.f);
            if (row < sz && jb < sz) {
                float si = (float)row * ratio;
                int   i0 = (int)si;
                float ti = si - (float)i0;
                int   i1 = min(i0 + 1, n - 1);
                const float* r0 = src + i0 * n;
                const float* r1 = src + i1 * n;
#pragma unroll
                for (int q = 0; q < 4; ++q) {
                    int   j  = jb + q;
                    float sj = (float)j * ratio;
                    int   j0 = (int)sj;
                    float tj = sj - (float)j0;
                    int   j1 = min(j0 + 1, n - 1);
                    float a0 = r0[j0], b0 = r1[j0];
                    float a1 = r0[j1], b1 = r1[j1];
                    float c0 = a0 + ti * (b0 - a0);
                    float c1 = a1 + ti * (b1 - a1);
                    v[q] = c0 + tj * (c1 - c0);
                }
            }
            outp[idx] = v;
        }
    }
}

extern "C" void kernel_launch(void* const* d_in, const int* in_sizes, int n_in,
                              void* d_out, int out_size, void* d_ws, size_t ws_size,
                              hipStream_t stream) {
    const float* x0   = (const float*)d_in[0];
    const float* x1   = (const float*)d_in[1];
    const float* x2   = (const float*)d_in[2];
    const float* x3   = (const float*)d_in[3];
    const float* rois = (const float*)d_in[4];
    float* out = (float*)d_out;

    dim3 grid(CCH, NROIS);  // (channel, roi) -> 4096 blocks
    roi_level_kernel<<<grid, NT, 0, stream>>>(x0, x1, x2, x3, rois, out);
}

// Round 7
// 43.139 us; speedup vs baseline: 1.1777x; 1.1777x over previous
//
#include <hip/hip_runtime.h>

#define NROIS 64
#define CCH   64
#define OUTD  128
#define NT    512   // threads per block (swept: 256->44.6us, 512->43.4us, 1024->50.8us)

typedef float f32x4 __attribute__((ext_vector_type(4)));

// One 2x align_corners=True bilinear upsample step inside LDS.
// src: N x N, dst: 2N x 2N. Matches reference lin1d(axis=H) then lin1d(axis=W).
template <int N>
__device__ __forceinline__ void up2x_lds(const float* __restrict__ src,
                                         float* __restrict__ dst, int tid) {
    constexpr int N2 = 2 * N;
    constexpr float ratio = (float)(N - 1) / (float)(N2 - 1);
    for (int idx = tid; idx < N2 * N2; idx += NT) {
        int i = idx / N2;
        int j = idx - i * N2;
        float si = (float)i * ratio;
        int i0 = (int)si;
        float ti = si - (float)i0;
        int i1 = min(i0 + 1, N - 1);
        float sj = (float)j * ratio;
        int j0 = (int)sj;
        float tj = sj - (float)j0;
        int j1 = min(j0 + 1, N - 1);
        float a00 = src[i0 * N + j0], a10 = src[i1 * N + j0];
        float a01 = src[i0 * N + j1], a11 = src[i1 * N + j1];
        float c0 = a00 + ti * (a10 - a00);
        float c1 = a01 + ti * (a11 - a01);
        dst[idx] = c0 + tj * (c1 - c0);
    }
}

__global__ __launch_bounds__(NT) void roi_level_kernel(
    const float* __restrict__ x0, const float* __restrict__ x1,
    const float* __restrict__ x2, const float* __restrict__ x3,
    const float* __restrict__ rois, float* __restrict__ out) {
    __shared__ float s16[16 * 16];
    __shared__ float s32[32 * 32];
    __shared__ float s64[64 * 64];

    const int c   = blockIdx.x;   // channel (fastest -> contiguous 64KB writes)
    const int r   = blockIdx.y;   // roi
    const int tid = threadIdx.x;

    // ---- per-ROI params (block-uniform) ----
    const float* R = rois + r * 5;
    const float px = R[1], py = R[2], w = R[3], h = R[4];
    const int   b  = (int)R[0];
    float s = sqrtf(w * h);
    float target = floorf(4.0f + log2f(s / 224.0f + 1e-6f));
    target = fminf(fmaxf(target, 2.0f), 5.0f);
    const int level = (int)target - 2;               // 0..3
    const float scale = 1.0f / (float)(4 << level);
    const int xl = ((int)(px * scale)) & ~1;
    const int yl = ((int)(py * scale)) & ~1;
    const float* feat = (level == 0) ? x0 : (level == 1) ? x1
                       : (level == 2) ? x2 : x3;
    const int H = 256 >> level;

    // ---- load 16x16 crop for this channel into LDS ----
    if (tid < 256) {
        int i = tid >> 4, j = tid & 15;
        s16[tid] = feat[(((size_t)b * CCH + c) * H + (size_t)(yl + i)) * H + (xl + j)];
    }
    __syncthreads();

    // ---- pre-upsample steps in LDS ----
    if (level >= 2) { up2x_lds<16>(s16, s32, tid); __syncthreads(); }
    if (level == 3) { up2x_lds<32>(s32, s64, tid); __syncthreads(); }

    // ---- final step fused with the padded 128x128 write ----
    f32x4* outp = (f32x4*)(out + ((size_t)(r * CCH + c) << 14));  // 128*128 plane

    if (level == 0) {
        for (int k = 0; k < 8; ++k) {
            int idx  = tid + k * NT;          // 0..4095 float4 slots
            int row  = idx >> 5;              // 32 float4 per row
            int col4 = idx & 31;
            f32x4 v = (f32x4)(0.f);
            if (row < 16 && col4 < 4) {
                const float* p = s16 + row * 16 + col4 * 4;
                v = (f32x4){p[0], p[1], p[2], p[3]};
            }
            outp[idx] = v;
        }
    } else {
        const float* src = (level == 1) ? s16 : (level == 2) ? s32 : s64;
        const int   n     = 8 << level;       // source grid dim
        const int   sz    = n * 2;            // nonzero extent (32/64/128)
        const float ratio = (float)(n - 1) / (float)(2 * n - 1);
        for (int k = 0; k < 8; ++k) {
            int idx  = tid + k * NT;
            int row  = idx >> 5;
            int jb   = (idx & 31) * 4;
            f32x4 v = (f32x4)(0.f);
            if (row < sz && jb < sz) {
                float si = (float)row * ratio;
                int   i0 = (int)si;
                float ti = si - (float)i0;
                int   i1 = min(i0 + 1, n - 1);
                const float* r0 = src + i0 * n;
                const float* r1 = src + i1 * n;
#pragma unroll
                for (int q = 0; q < 4; ++q) {
                    int   j  = jb + q;
                    float sj = (float)j * ratio;
                    int   j0 = (int)sj;
                    float tj = sj - (float)j0;
                    int   j1 = min(j0 + 1, n - 1);
                    float a0 = r0[j0], b0 = r1[j0];
                    float a1 = r0[j1], b1 = r1[j1];
                    float c0 = a0 + ti * (b0 - a0);
                    float c1 = a1 + ti * (b1 - a1);
                    v[q] = c0 + tj * (c1 - c0);
                }
            }
            outp[idx] = v;
        }
    }
}

extern "C" void kernel_launch(void* const* d_in, const int* in_sizes, int n_in,
                              void* d_out, int out_size, void* d_ws, size_t ws_size,
                              hipStream_t stream) {
    const float* x0   = (const float*)d_in[0];
    const float* x1   = (const float*)d_in[1];
    const float* x2   = (const float*)d_in[2];
    const float* x3   = (const float*)d_in[3];
    const float* rois = (const float*)d_in[4];
    float* out = (float*)d_out;

    dim3 grid(CCH, NROIS);  // (channel, roi) -> 2048 blocks
    roi_level_kernel<<<grid, NT, 0, stream>>>(x0, x1, x2, x3, rois, out);
}